// Round 2
// baseline (989.380 us; speedup 1.0000x reference)
//
#include <hip/hip_runtime.h>
#include <math.h>

#define N_ 32
#define D_ 512
#define S_ 1600
#define K_ 64

// ---------------------------------------------------------------------------
// Kernel A: fused per-pixel L2-norm + 1x1 conv (logits) + softmax.
//   aprime[n][k][s] = softmax_k(logits) * invnorm(n,s)  (agg then uses raw x)
//   asum[n][k]     += softmax_k                          (atomic)
// grid: 800 blocks x 64 threads (1 wave), lane = pixel.
// w accesses are wave-uniform -> compiler emits s_load (scalar pipe, no LDS);
// x staged 32 channels at a time into VGPRs so loads batch & overlap compute.
// ---------------------------------------------------------------------------
__global__ __launch_bounds__(64) void kA(const float* __restrict__ x,
                                         const float* __restrict__ w,
                                         float* __restrict__ aprime,
                                         float* __restrict__ asum)
{
    const int tid = threadIdx.x;
    const int blk = blockIdx.x;
    const int n = blk / 25;
    const int s = (blk % 25) * 64 + tid;

    const float* xb = x + (size_t)n * D_ * S_ + s;

    float acc[K_];
#pragma unroll
    for (int k = 0; k < K_; ++k) acc[k] = 0.f;
    float ss = 0.f;

    for (int dc = 0; dc < D_; dc += 32) {
        // batch-load 32 channels into registers: 32 independent coalesced loads
        float xv[32];
#pragma unroll
        for (int i = 0; i < 32; ++i) xv[i] = xb[(size_t)(dc + i) * S_];
#pragma unroll
        for (int i = 0; i < 32; ++i) ss += xv[i] * xv[i];

#pragma unroll
        for (int k = 0; k < K_; ++k) {
            const float* wr = w + k * D_ + dc;   // uniform address -> s_load
#pragma unroll
            for (int i = 0; i < 32; ++i) acc[k] += wr[i] * xv[i];
        }
    }

    const float inv = 1.0f / fmaxf(sqrtf(ss), 1e-12f);

    // stable softmax over k of (acc[k]*inv); inv>0 so max commutes with scale
    float m = -1e30f;
#pragma unroll
    for (int k = 0; k < K_; ++k) m = fmaxf(m, acc[k]);
    float sum = 0.f;
#pragma unroll
    for (int k = 0; k < K_; ++k) {
        acc[k] = __expf((acc[k] - m) * inv);
        sum += acc[k];
    }
    const float rs = 1.0f / sum;

    float* apb = aprime + (size_t)n * K_ * S_ + s;
#pragma unroll
    for (int k = 0; k < K_; ++k) {
        float a = acc[k] * rs;
        apb[(size_t)k * S_] = a * inv;   // coalesced over lanes
        float v = a;
        v += __shfl_xor(v, 32);
        v += __shfl_xor(v, 16);
        v += __shfl_xor(v, 8);
        v += __shfl_xor(v, 4);
        v += __shfl_xor(v, 2);
        v += __shfl_xor(v, 1);
        if (tid == 0) atomicAdd(&asum[n * K_ + k], v);
    }
}

// ---------------------------------------------------------------------------
// Kernel B: partial agg[n][k][d] = sum_{s in split} aprime[n][k][s] * x[n][d][s]
// grid: 32 n * 8 d-tiles * 4 s-splits = 1024 blocks x 256 threads.
// Each split writes its own partial buffer (deterministic; kC sums them).
// ---------------------------------------------------------------------------
__global__ __launch_bounds__(256) void kB(const float* __restrict__ x,
                                          const float* __restrict__ aprime,
                                          float* __restrict__ aggp)
{
    __shared__ float la[64 * 68];   // [sc][k]
    __shared__ float lx[64 * 68];   // [sc][dd]
    const int tid = threadIdx.x;
    const int b = blockIdx.x;
    const int n     = b >> 5;
    const int d0    = ((b >> 2) & 7) * 64;
    const int split = b & 3;
    const int lane_k = (tid & 15) * 4;
    const int lane_d = (tid >> 4) * 4;

    float acc[4][4];
#pragma unroll
    for (int i = 0; i < 4; ++i)
#pragma unroll
        for (int j = 0; j < 4; ++j) acc[i][j] = 0.f;

    const float* apb = aprime + (size_t)n * K_ * S_;
    const float* xb  = x + (size_t)n * D_ * S_ + (size_t)d0 * S_;

    for (int s0 = split * 64; s0 < S_; s0 += 256) {
        __syncthreads();
#pragma unroll
        for (int j = 0; j < 16; ++j) {
            int i   = tid + j * 256;
            int row = i >> 6;        // k (for la) / dd (for lx)
            int sc  = i & 63;
            la[sc * 68 + row] = apb[(size_t)row * S_ + s0 + sc];
            lx[sc * 68 + row] = xb[(size_t)row * S_ + s0 + sc];
        }
        __syncthreads();

#pragma unroll 4
        for (int sc = 0; sc < 64; ++sc) {
            float4 av = *(const float4*)&la[sc * 68 + lane_k];
            float4 xv = *(const float4*)&lx[sc * 68 + lane_d];
            float a4[4] = {av.x, av.y, av.z, av.w};
            float x4[4] = {xv.x, xv.y, xv.z, xv.w};
#pragma unroll
            for (int i = 0; i < 4; ++i)
#pragma unroll
                for (int j = 0; j < 4; ++j) acc[i][j] += a4[i] * x4[j];
        }
    }

    float* ab = aggp + (size_t)split * N_ * K_ * D_ + (size_t)n * K_ * D_;
#pragma unroll
    for (int i = 0; i < 4; ++i) {
        float4 st = {acc[i][0], acc[i][1], acc[i][2], acc[i][3]};
        *(float4*)&ab[(size_t)(lane_k + i) * D_ + d0 + lane_d] = st;
    }
}

// ---------------------------------------------------------------------------
// Kernel C: vlad = (sum of 4 agg partials) - asum*centroid; intra-L2-norm
// over d; global norm = /sqrt(K) = /8 exactly (rows are unit-norm post intra).
// grid: 2048 blocks x 256 threads; 2 elements/thread.
// ---------------------------------------------------------------------------
__global__ __launch_bounds__(256) void kC(const float* __restrict__ aggp,
                                          const float* __restrict__ asum,
                                          const float* __restrict__ cent,
                                          float* __restrict__ out)
{
    __shared__ float red[4];
    const int tid = threadIdx.x;
    const int nk = blockIdx.x;
    const int k = nk & 63;
    const float as = asum[nk];
    const float* cb = cent + (size_t)k * D_;

    float v0 = 0.f, v1 = 0.f;
#pragma unroll
    for (int p = 0; p < 4; ++p) {
        const float* ag = aggp + (size_t)p * N_ * K_ * D_ + (size_t)nk * D_;
        v0 += ag[tid];
        v1 += ag[tid + 256];
    }
    v0 -= as * cb[tid];
    v1 -= as * cb[tid + 256];
    float ssq = v0 * v0 + v1 * v1;

    ssq += __shfl_xor(ssq, 32);
    ssq += __shfl_xor(ssq, 16);
    ssq += __shfl_xor(ssq, 8);
    ssq += __shfl_xor(ssq, 4);
    ssq += __shfl_xor(ssq, 2);
    ssq += __shfl_xor(ssq, 1);
    const int wave = tid >> 6;
    if ((tid & 63) == 0) red[wave] = ssq;
    __syncthreads();
    const float total = red[0] + red[1] + red[2] + red[3];
    const float scale = 1.0f / (fmaxf(sqrtf(total), 1e-12f) * 8.0f);

    out[(size_t)nk * D_ + tid]       = v0 * scale;
    out[(size_t)nk * D_ + tid + 256] = v1 * scale;
}

// ---------------------------------------------------------------------------
extern "C" void kernel_launch(void* const* d_in, const int* in_sizes, int n_in,
                              void* d_out, int out_size, void* d_ws, size_t ws_size,
                              hipStream_t stream)
{
    const float* x    = (const float*)d_in[0];   // [32,512,40,40]
    const float* w    = (const float*)d_in[1];   // [64,512]
    const float* cent = (const float*)d_in[2];   // [64,512]
    float* out = (float*)d_out;                  // [32, 32768]

    float* aprime = (float*)d_ws;                          // N*K*S       = 3,276,800 f
    float* asum   = aprime + (size_t)N_ * K_ * S_;         // N*K         = 2,048 f
    float* aggp   = asum + (size_t)N_ * K_;                // 4 * N*K*D   = 4,194,304 f

    hipMemsetAsync(asum, 0, (size_t)N_ * K_ * sizeof(float), stream);

    kA<<<N_ * (S_ / 64), 64, 0, stream>>>(x, w, aprime, asum);
    kB<<<N_ * 8 * 4, 256, 0, stream>>>(x, aprime, aggp);
    kC<<<N_ * K_, 256, 0, stream>>>(aggp, asum, cent, out);
}

// Round 3
// 267.620 us; speedup vs baseline: 3.6970x; 3.6970x over previous
//
#include <hip/hip_runtime.h>
#include <math.h>

#define N_ 32
#define D_ 512
#define S_ 1600
#define K_ 64

// ---------------------------------------------------------------------------
// Kernel A: tiled GEMM logits[k][s] = sum_d w[k][d] x[n][d][s], fused with
// per-pixel L2-norm (x^2 accumulated from the same staged tile) and softmax
// over k (wave-local shfl reduction across the 16 k-lane-groups).
//   aprime[n][k][s] = softmax_k * invnorm(n,s)
//   asum[n][k]     += softmax_k   (atomic, zeroed first)
// grid: N * S/64 = 800 blocks x 256 threads (4 waves). Each wave: all 64 k,
// 16 s-columns. lane_k=(tid&15)*4, lane_s=(tid>>4)*4.
// ---------------------------------------------------------------------------
__global__ __launch_bounds__(256) void kA(const float* __restrict__ x,
                                          const float* __restrict__ w,
                                          float* __restrict__ aprime,
                                          float* __restrict__ asum)
{
    __shared__ float la[64 * 68];   // [dci][k]  stride 68: b128 ops at phase floor
    __shared__ float lx[64 * 68];   // [dci][s]
    const int tid = threadIdx.x;
    const int n  = blockIdx.x / 25;
    const int s0 = (blockIdx.x % 25) * 64;
    const int lane_k = (tid & 15) * 4;
    const int lane_s = (tid >> 4) * 4;   // tid>>4 in 0..15 across the 4 waves

    const float* xn = x + (size_t)n * D_ * S_;

    float acc[4][4];
#pragma unroll
    for (int i = 0; i < 4; ++i)
#pragma unroll
        for (int j = 0; j < 4; ++j) acc[i][j] = 0.f;
    float ssq[4] = {0.f, 0.f, 0.f, 0.f};

    for (int dc = 0; dc < D_; dc += 64) {
        __syncthreads();
        // stage w-tile transposed: la[dci][k] = w[k][dc+dci]
        {
            const int dci = tid & 63;
#pragma unroll
            for (int q = 0; q < 4; ++q) {
                int k0 = ((tid >> 6) + 4 * q) * 4;   // 16 k-groups of 4
                float4 wv;
                wv.x = w[(k0 + 0) * D_ + dc + dci];
                wv.y = w[(k0 + 1) * D_ + dc + dci];
                wv.z = w[(k0 + 2) * D_ + dc + dci];
                wv.w = w[(k0 + 3) * D_ + dc + dci];
                *(float4*)&la[dci * 68 + k0] = wv;
            }
        }
        // stage x-tile: lx[dci][s] = x[n][dc+dci][s0+s], float4 both sides
        {
            const int sg = (tid & 15) * 4;
#pragma unroll
            for (int r = 0; r < 4; ++r) {
                int dcx = (tid >> 4) + 16 * r;
                float4 xv = *(const float4*)&xn[(size_t)(dc + dcx) * S_ + s0 + sg];
                *(float4*)&lx[dcx * 68 + sg] = xv;
            }
        }
        __syncthreads();

#pragma unroll 8
        for (int dci = 0; dci < 64; ++dci) {
            float4 av = *(const float4*)&la[dci * 68 + lane_k];
            float4 xv = *(const float4*)&lx[dci * 68 + lane_s];
            float a4[4] = {av.x, av.y, av.z, av.w};
            float x4[4] = {xv.x, xv.y, xv.z, xv.w};
            ssq[0] += x4[0] * x4[0];
            ssq[1] += x4[1] * x4[1];
            ssq[2] += x4[2] * x4[2];
            ssq[3] += x4[3] * x4[3];
#pragma unroll
            for (int i = 0; i < 4; ++i)
#pragma unroll
                for (int j = 0; j < 4; ++j) acc[i][j] += a4[i] * x4[j];
        }
    }

    // epilogue: per s-column j, softmax over the 64 k (4 local x 16 lanes)
    float p[4][4];
    float invs[4];
#pragma unroll
    for (int j = 0; j < 4; ++j) {
        float m = fmaxf(fmaxf(acc[0][j], acc[1][j]), fmaxf(acc[2][j], acc[3][j]));
        m = fmaxf(m, __shfl_xor(m, 1));
        m = fmaxf(m, __shfl_xor(m, 2));
        m = fmaxf(m, __shfl_xor(m, 4));
        m = fmaxf(m, __shfl_xor(m, 8));
        const float inv = 1.0f / fmaxf(sqrtf(ssq[j]), 1e-12f);
        float sum = 0.f;
#pragma unroll
        for (int i = 0; i < 4; ++i) {
            float e = __expf((acc[i][j] - m) * inv);
            p[i][j] = e;
            sum += e;
        }
        sum += __shfl_xor(sum, 1);
        sum += __shfl_xor(sum, 2);
        sum += __shfl_xor(sum, 4);
        sum += __shfl_xor(sum, 8);
        const float rs = 1.0f / sum;
#pragma unroll
        for (int i = 0; i < 4; ++i) p[i][j] *= rs;
        invs[j] = inv;
    }

    // store aprime = p * invnorm  (float4 per k-row)
    float* apb = aprime + (size_t)n * K_ * S_ + s0 + lane_s;
#pragma unroll
    for (int i = 0; i < 4; ++i) {
        float4 st = {p[i][0] * invs[0], p[i][1] * invs[1],
                     p[i][2] * invs[2], p[i][3] * invs[3]};
        *(float4*)&apb[(size_t)(lane_k + i) * S_] = st;
    }

    // asum: sum p over this wave's 16 s-columns, one atomic per (k) from 16 lanes
#pragma unroll
    for (int i = 0; i < 4; ++i) {
        float t = p[i][0] + p[i][1] + p[i][2] + p[i][3];
        t += __shfl_xor(t, 16);
        t += __shfl_xor(t, 32);
        if ((tid & 63) < 16) atomicAdd(&asum[n * K_ + lane_k + i], t);
    }
}

// ---------------------------------------------------------------------------
// Kernel B: partial agg[n][k][d] = sum_{s in split} aprime[n][k][s] * x[n][d][s]
// grid: 32 n * 8 d-tiles * 4 s-splits = 1024 blocks x 256 threads.
// Each split writes its own partial buffer (deterministic; kC sums them).
// ---------------------------------------------------------------------------
__global__ __launch_bounds__(256) void kB(const float* __restrict__ x,
                                          const float* __restrict__ aprime,
                                          float* __restrict__ aggp)
{
    __shared__ float la[64 * 68];   // [sc][k]
    __shared__ float lx[64 * 68];   // [sc][dd]
    const int tid = threadIdx.x;
    const int b = blockIdx.x;
    const int n     = b >> 5;
    const int d0    = ((b >> 2) & 7) * 64;
    const int split = b & 3;
    const int lane_k = (tid & 15) * 4;
    const int lane_d = (tid >> 4) * 4;

    float acc[4][4];
#pragma unroll
    for (int i = 0; i < 4; ++i)
#pragma unroll
        for (int j = 0; j < 4; ++j) acc[i][j] = 0.f;

    const float* apb = aprime + (size_t)n * K_ * S_;
    const float* xb  = x + (size_t)n * D_ * S_ + (size_t)d0 * S_;

    for (int s0 = split * 64; s0 < S_; s0 += 256) {
        __syncthreads();
#pragma unroll
        for (int j = 0; j < 16; ++j) {
            int i   = tid + j * 256;
            int row = i >> 6;        // k (for la) / dd (for lx)
            int sc  = i & 63;
            la[sc * 68 + row] = apb[(size_t)row * S_ + s0 + sc];
            lx[sc * 68 + row] = xb[(size_t)row * S_ + s0 + sc];
        }
        __syncthreads();

#pragma unroll 4
        for (int sc = 0; sc < 64; ++sc) {
            float4 av = *(const float4*)&la[sc * 68 + lane_k];
            float4 xv = *(const float4*)&lx[sc * 68 + lane_d];
            float a4[4] = {av.x, av.y, av.z, av.w};
            float x4[4] = {xv.x, xv.y, xv.z, xv.w};
#pragma unroll
            for (int i = 0; i < 4; ++i)
#pragma unroll
                for (int j = 0; j < 4; ++j) acc[i][j] += a4[i] * x4[j];
        }
    }

    float* ab = aggp + (size_t)split * N_ * K_ * D_ + (size_t)n * K_ * D_;
#pragma unroll
    for (int i = 0; i < 4; ++i) {
        float4 st = {acc[i][0], acc[i][1], acc[i][2], acc[i][3]};
        *(float4*)&ab[(size_t)(lane_k + i) * D_ + d0 + lane_d] = st;
    }
}

// ---------------------------------------------------------------------------
// Kernel C: vlad = (sum of 4 agg partials) - asum*centroid; intra-L2-norm
// over d; global norm = /sqrt(K) = /8 exactly (rows are unit-norm post intra).
// grid: 2048 blocks x 256 threads; 2 elements/thread.
// ---------------------------------------------------------------------------
__global__ __launch_bounds__(256) void kC(const float* __restrict__ aggp,
                                          const float* __restrict__ asum,
                                          const float* __restrict__ cent,
                                          float* __restrict__ out)
{
    __shared__ float red[4];
    const int tid = threadIdx.x;
    const int nk = blockIdx.x;
    const int k = nk & 63;
    const float as = asum[nk];
    const float* cb = cent + (size_t)k * D_;

    float v0 = 0.f, v1 = 0.f;
#pragma unroll
    for (int p = 0; p < 4; ++p) {
        const float* ag = aggp + (size_t)p * N_ * K_ * D_ + (size_t)nk * D_;
        v0 += ag[tid];
        v1 += ag[tid + 256];
    }
    v0 -= as * cb[tid];
    v1 -= as * cb[tid + 256];
    float ssq = v0 * v0 + v1 * v1;

    ssq += __shfl_xor(ssq, 32);
    ssq += __shfl_xor(ssq, 16);
    ssq += __shfl_xor(ssq, 8);
    ssq += __shfl_xor(ssq, 4);
    ssq += __shfl_xor(ssq, 2);
    ssq += __shfl_xor(ssq, 1);
    const int wave = tid >> 6;
    if ((tid & 63) == 0) red[wave] = ssq;
    __syncthreads();
    const float total = red[0] + red[1] + red[2] + red[3];
    const float scale = 1.0f / (fmaxf(sqrtf(total), 1e-12f) * 8.0f);

    out[(size_t)nk * D_ + tid]       = v0 * scale;
    out[(size_t)nk * D_ + tid + 256] = v1 * scale;
}

// ---------------------------------------------------------------------------
extern "C" void kernel_launch(void* const* d_in, const int* in_sizes, int n_in,
                              void* d_out, int out_size, void* d_ws, size_t ws_size,
                              hipStream_t stream)
{
    const float* x    = (const float*)d_in[0];   // [32,512,40,40]
    const float* w    = (const float*)d_in[1];   // [64,512]
    const float* cent = (const float*)d_in[2];   // [64,512]
    float* out = (float*)d_out;                  // [32, 32768]

    float* aprime = (float*)d_ws;                          // N*K*S       = 3,276,800 f
    float* asum   = aprime + (size_t)N_ * K_ * S_;         // N*K         = 2,048 f
    float* aggp   = asum + (size_t)N_ * K_;                // 4 * N*K*D   = 4,194,304 f

    hipMemsetAsync(asum, 0, (size_t)N_ * K_ * sizeof(float), stream);

    kA<<<N_ * (S_ / 64), 256, 0, stream>>>(x, w, aprime, asum);
    kB<<<N_ * 8 * 4, 256, 0, stream>>>(x, aprime, aggp);
    kC<<<N_ * K_, 256, 0, stream>>>(aggp, asum, cent, out);
}

// Round 4
// 203.529 us; speedup vs baseline: 4.8611x; 1.3149x over previous
//
#include <hip/hip_runtime.h>
#include <math.h>

#define N_ 32
#define D_ 512
#define S_ 1600
#define K_ 64

typedef __attribute__((ext_vector_type(8))) short short8;   // 8 bf16 = 16 B (A/B frag)
typedef __attribute__((ext_vector_type(4))) float f32x4;    // acc frag

// float -> bf16 (round to nearest even), bit pattern in short
static __device__ __forceinline__ short f2bf(float f) {
    unsigned u = __float_as_uint(f);
    u += 0x7fffu + ((u >> 16) & 1u);
    return (short)(u >> 16);
}

// ---------------------------------------------------------------------------
// kW: convert conv_weight [64][512] fp32 -> bf16
// ---------------------------------------------------------------------------
__global__ __launch_bounds__(256) void kW(const float* __restrict__ w,
                                          short* __restrict__ w16)
{
    int i4 = (blockIdx.x * 256 + threadIdx.x) * 4;   // 32 blocks: 32768 elems
    float4 v = *(const float4*)&w[i4];
    short4 h = {f2bf(v.x), f2bf(v.y), f2bf(v.z), f2bf(v.w)};
    *(short4*)&w16[i4] = h;
}

// ---------------------------------------------------------------------------
// kA: logits[k][s] = sum_d w16[k][d] * xbf[d][s]  via MFMA (raw x, no norm),
// fused ssq (from staged fp32), softmax over k of logits*inv in fp32.
//   aprime[n][k][s] = softmax * inv   (bf16, for kB against raw x)
//   asum[n][k]     += softmax          (fp32 atomics)
// grid: N*25 = 800 blocks x 256 thr (4 waves). block tile: 64 k x 64 s.
// wave wv: k in [16wv,16wv+16). MFMA conv: A-frag m=lane&15, B-frag n=lane&15,
// D[row=4q+r][col=lane&15], row<-first operand (k), col<-second (s).
// ---------------------------------------------------------------------------
#define TP 72   // T row pitch in bf16 (144 B: 16B-aligned rows)

__global__ __launch_bounds__(256) void kA(const float* __restrict__ x,
                                          const short* __restrict__ w16,
                                          short* __restrict__ aprime,
                                          float* __restrict__ asum)
{
    __shared__ short T[64 * TP];        // [s][d-chunk] transposed bf16 tile (18 KB)
    __shared__ float pssq[16 * 66];     // per-drow-group partial ssq
    __shared__ float invL[64];
    __shared__ float wred[2][4][64];    // cross-wave max / sum buffers

    const int tid = threadIdx.x;
    const int n  = blockIdx.x / 25;
    const int s0 = (blockIdx.x % 25) * 64;
    const int wv = tid >> 6;
    const int l  = tid & 63;
    const int lk = l & 15;      // col id (s-offset within 16-tile)
    const int q  = l >> 4;      // quad

    const float* xb = x + (size_t)n * D_ * S_ + s0;
    const int sg = (tid & 15) * 4;      // staging: 4 s-cols per thread
    const int dg = tid >> 4;            // staging: d-row group 0..15

    f32x4 acc[4];
#pragma unroll
    for (int st = 0; st < 4; ++st) acc[st] = (f32x4){0.f, 0.f, 0.f, 0.f};
    float ssql[4] = {0.f, 0.f, 0.f, 0.f};

    for (int dc = 0; dc < D_; dc += 64) {
        __syncthreads();
        // stage x[dc..dc+64)[s0..s0+64) -> T[s][dci] bf16, ssq alongside
#pragma unroll
        for (int j = 0; j < 4; ++j) {
            int dci = dg + 16 * j;
            float4 v = *(const float4*)&xb[(size_t)(dc + dci) * S_ + sg];
            ssql[0] += v.x * v.x;  ssql[1] += v.y * v.y;
            ssql[2] += v.z * v.z;  ssql[3] += v.w * v.w;
            T[(sg + 0) * TP + dci] = f2bf(v.x);
            T[(sg + 1) * TP + dci] = f2bf(v.y);
            T[(sg + 2) * TP + dci] = f2bf(v.z);
            T[(sg + 3) * TP + dci] = f2bf(v.w);
        }
        __syncthreads();

#pragma unroll
        for (int kst = 0; kst < 2; ++kst) {
            // A-frag: w16[16wv+lk][dc + 32kst + 8q .. +7]
            short8 af = *(const short8*)&w16[(16 * wv + lk) * D_ + dc + kst * 32 + q * 8];
#pragma unroll
            for (int st = 0; st < 4; ++st) {
                short8 bf = *(const short8*)&T[(st * 16 + lk) * TP + kst * 32 + q * 8];
                acc[st] = __builtin_amdgcn_mfma_f32_16x16x32_bf16(af, bf, acc[st], 0, 0, 0);
            }
        }
    }

    // reduce ssq: pssq[dg][s]
    __syncthreads();
#pragma unroll
    for (int i = 0; i < 4; ++i) pssq[dg * 66 + sg + i] = ssql[i];
    __syncthreads();
    if (tid < 64) {
        float ss = 0.f;
#pragma unroll
        for (int g = 0; g < 16; ++g) ss += pssq[g * 66 + tid];
        invL[tid] = 1.0f / fmaxf(sqrtf(ss), 1e-12f);
    }
    __syncthreads();

    // epilogue: logits lane view: lg[st][r] = logits[16wv+4q+r][st*16+lk] * inv
    float lg[4][4], invv[4];
#pragma unroll
    for (int st = 0; st < 4; ++st) {
        invv[st] = invL[st * 16 + lk];
#pragma unroll
        for (int r = 0; r < 4; ++r) lg[st][r] = acc[st][r] * invv[st];
    }
    // max over k: in-lane (4 r) -> cross-quad (x16, x32) -> cross-wave (LDS)
    float mx[4];
#pragma unroll
    for (int st = 0; st < 4; ++st) {
        float m = fmaxf(fmaxf(lg[st][0], lg[st][1]), fmaxf(lg[st][2], lg[st][3]));
        m = fmaxf(m, __shfl_xor(m, 16));
        m = fmaxf(m, __shfl_xor(m, 32));
        mx[st] = m;
        if (q == 0) wred[0][wv][st * 16 + lk] = m;
    }
    __syncthreads();
    float gm[4];
#pragma unroll
    for (int st = 0; st < 4; ++st) {
        float m = wred[0][0][st * 16 + lk];
        m = fmaxf(m, wred[0][1][st * 16 + lk]);
        m = fmaxf(m, wred[0][2][st * 16 + lk]);
        m = fmaxf(m, wred[0][3][st * 16 + lk]);
        gm[st] = m;
    }
    // exp + sum over k
    float e[4][4];
#pragma unroll
    for (int st = 0; st < 4; ++st) {
        float s = 0.f;
#pragma unroll
        for (int r = 0; r < 4; ++r) {
            e[st][r] = __expf(lg[st][r] - gm[st]);
            s += e[st][r];
        }
        s += __shfl_xor(s, 16);
        s += __shfl_xor(s, 32);
        if (q == 0) wred[1][wv][st * 16 + lk] = s;
    }
    __syncthreads();
    float rs[4];
#pragma unroll
    for (int st = 0; st < 4; ++st) {
        float s = wred[1][0][st * 16 + lk] + wred[1][1][st * 16 + lk]
                + wred[1][2][st * 16 + lk] + wred[1][3][st * 16 + lk];
        rs[st] = 1.0f / s;
    }

    // p = e*rs; store aprime = bf16(p*inv); asum += p
    short* apb = aprime + (size_t)n * K_ * S_ + s0;
#pragma unroll
    for (int r = 0; r < 4; ++r) {
        const int k = 16 * wv + 4 * q + r;
        float accp = 0.f;
#pragma unroll
        for (int st = 0; st < 4; ++st) {
            float p = e[st][r] * rs[st];
            apb[(size_t)k * S_ + st * 16 + lk] = f2bf(p * invv[st]);
            accp += p;
        }
        accp += __shfl_xor(accp, 1);
        accp += __shfl_xor(accp, 2);
        accp += __shfl_xor(accp, 4);
        accp += __shfl_xor(accp, 8);
        if (lk == 0) atomicAdd(&asum[n * K_ + k], accp);
    }
}

// ---------------------------------------------------------------------------
// kB: LDS-free MFMA GEMM. agg[k][d] partial over s-split:
//   agg[k][d] = sum_s aprime[k][s] * x[d][s]   (both s-contiguous row-major)
// grid: n(32) x dtile(4 of 128) x split(5 of 320s) = 640 blocks x 256 thr.
// wave wv: d in [dt*128 + wv*32, +32), all 64 k, 10 K-steps of 32 s.
// ---------------------------------------------------------------------------
__global__ __launch_bounds__(256) void kB(const float* __restrict__ x,
                                          const short* __restrict__ aprime,
                                          float* __restrict__ aggp)
{
    const int bid = blockIdx.x;
    const int n  = bid / 20;
    const int dt = (bid % 20) / 5;
    const int sp = bid % 5;
    const int wv = threadIdx.x >> 6;
    const int l  = threadIdx.x & 63;
    const int lk = l & 15;
    const int q  = l >> 4;
    const int dbase = dt * 128 + wv * 32;

    const short* ap = aprime + (size_t)n * K_ * S_;
    const float* xb = x + (size_t)n * D_ * S_;

    f32x4 acc[4][2];   // [ktile][dsub]
#pragma unroll
    for (int kt = 0; kt < 4; ++kt)
#pragma unroll
        for (int ds = 0; ds < 2; ++ds) acc[kt][ds] = (f32x4){0.f, 0.f, 0.f, 0.f};

    for (int kst = 0; kst < 10; ++kst) {
        const int s = sp * 320 + kst * 32 + q * 8;
        short8 af[4];
#pragma unroll
        for (int kt = 0; kt < 4; ++kt)
            af[kt] = *(const short8*)&ap[(size_t)(kt * 16 + lk) * S_ + s];
        short8 bf[2];
#pragma unroll
        for (int ds = 0; ds < 2; ++ds) {
            const float* xp = &xb[(size_t)(dbase + ds * 16 + lk) * S_ + s];
            float4 v0 = *(const float4*)xp;
            float4 v1 = *(const float4*)(xp + 4);
            short8 b;
            b[0] = f2bf(v0.x); b[1] = f2bf(v0.y); b[2] = f2bf(v0.z); b[3] = f2bf(v0.w);
            b[4] = f2bf(v1.x); b[5] = f2bf(v1.y); b[6] = f2bf(v1.z); b[7] = f2bf(v1.w);
            bf[ds] = b;
        }
#pragma unroll
        for (int kt = 0; kt < 4; ++kt)
#pragma unroll
            for (int ds = 0; ds < 2; ++ds)
                acc[kt][ds] = __builtin_amdgcn_mfma_f32_16x16x32_bf16(af[kt], bf[ds], acc[kt][ds], 0, 0, 0);
    }

    // store partial: aggp[sp][n][k][d]; D row=4q+r (k, 1st op), col=lk (d, 2nd op)
    float* ab = aggp + ((size_t)sp * N_ + n) * K_ * D_;
#pragma unroll
    for (int kt = 0; kt < 4; ++kt)
#pragma unroll
        for (int ds = 0; ds < 2; ++ds)
#pragma unroll
            for (int r = 0; r < 4; ++r)
                ab[(size_t)(kt * 16 + 4 * q + r) * D_ + dbase + ds * 16 + lk] = acc[kt][ds][r];
}

// ---------------------------------------------------------------------------
// kC: vlad = (sum of 5 agg partials) - asum*centroid; intra-L2-norm over d;
// global norm = /sqrt(K) = /8 exactly. grid: 2048 blocks x 256 thr.
// ---------------------------------------------------------------------------
__global__ __launch_bounds__(256) void kC(const float* __restrict__ aggp,
                                          const float* __restrict__ asum,
                                          const float* __restrict__ cent,
                                          float* __restrict__ out)
{
    __shared__ float red[4];
    const int tid = threadIdx.x;
    const int nk = blockIdx.x;
    const int k = nk & 63;
    const float as = asum[nk];
    const float* cb = cent + (size_t)k * D_;

    float v0 = 0.f, v1 = 0.f;
#pragma unroll
    for (int p = 0; p < 5; ++p) {
        const float* ag = aggp + (size_t)p * N_ * K_ * D_ + (size_t)nk * D_;
        v0 += ag[tid];
        v1 += ag[tid + 256];
    }
    v0 -= as * cb[tid];
    v1 -= as * cb[tid + 256];
    float ssq = v0 * v0 + v1 * v1;

    ssq += __shfl_xor(ssq, 32);
    ssq += __shfl_xor(ssq, 16);
    ssq += __shfl_xor(ssq, 8);
    ssq += __shfl_xor(ssq, 4);
    ssq += __shfl_xor(ssq, 2);
    ssq += __shfl_xor(ssq, 1);
    if ((tid & 63) == 0) red[tid >> 6] = ssq;
    __syncthreads();
    const float total = red[0] + red[1] + red[2] + red[3];
    const float scale = 1.0f / (fmaxf(sqrtf(total), 1e-12f) * 8.0f);

    out[(size_t)nk * D_ + tid]       = v0 * scale;
    out[(size_t)nk * D_ + tid + 256] = v1 * scale;
}

// ---------------------------------------------------------------------------
extern "C" void kernel_launch(void* const* d_in, const int* in_sizes, int n_in,
                              void* d_out, int out_size, void* d_ws, size_t ws_size,
                              hipStream_t stream)
{
    const float* x    = (const float*)d_in[0];   // [32,512,40,40]
    const float* w    = (const float*)d_in[1];   // [64,512]
    const float* cent = (const float*)d_in[2];   // [64,512]
    float* out = (float*)d_out;                  // [32, 32768]

    // ws carve (~28 MB): floats first (16B-aligned throughout)
    float* aggp   = (float*)d_ws;                          // 5*32*64*512 fp32
    float* asum   = aggp + (size_t)5 * N_ * K_ * D_;       // 2048 fp32
    short* aprime = (short*)(asum + N_ * K_);              // 32*64*1600 bf16
    short* w16    = aprime + (size_t)N_ * K_ * S_;         // 32768 bf16

    hipMemsetAsync(asum, 0, (size_t)N_ * K_ * sizeof(float), stream);

    kW<<<32, 256, 0, stream>>>(w, w16);
    kA<<<N_ * (S_ / 64), 256, 0, stream>>>(x, w16, aprime, asum);
    kB<<<N_ * 4 * 5, 256, 0, stream>>>(x, aprime, aggp);
    kC<<<N_ * K_, 256, 0, stream>>>(aggp, asum, cent, out);
}